// Round 1
// baseline (2096.387 us; speedup 1.0000x reference)
//
#include <hip/hip_runtime.h>
#include <cstdint>
#include <cstddef>

// Problem constants
#define B_DIM 8
#define T_DIM 2048
#define C_DIM 1024
#define D_DIM 64

#define NEG_BIG (-3.402823e38f)

// ---------------------------------------------------------------------------
// Kernel 1: QKV projection.  q/k/v[b,t,d] = sum_c x[b,t,c] * W[c,d] + bias[d]
// Block = 256 threads (4 lane-groups of 64), each block computes 16 t-rows.
// Lanes read W[c*64+d] coalesced (64 consecutive floats); x read as float4
// broadcast per row. Weights (768 KB) stream through L1 once per block:
// 1024 blocks * 768 KB = 768 MB of L2 traffic (~20-30 us at L2 BW).
// ---------------------------------------------------------------------------
__global__ __launch_bounds__(256) void qkv_proj_kernel(
    const float* __restrict__ x,
    const float* __restrict__ Wq, const float* __restrict__ bq,
    const float* __restrict__ Wk, const float* __restrict__ bk,
    const float* __restrict__ Wv, const float* __restrict__ bv,
    float* __restrict__ Q, float* __restrict__ Ko, float* __restrict__ Vo)
{
    const int tid = threadIdx.x;
    const int d   = tid & 63;
    const int g   = tid >> 6;                  // 0..3
    const size_t t0 = (size_t)blockIdx.x * 16; // 16 rows per block

    float aq[4], ak[4], av[4];
#pragma unroll
    for (int j = 0; j < 4; ++j) { aq[j] = 0.f; ak[j] = 0.f; av[j] = 0.f; }

    const float* xrow[4];
#pragma unroll
    for (int j = 0; j < 4; ++j) xrow[j] = x + (t0 + (size_t)g + 4u * j) * C_DIM;

    for (int c4 = 0; c4 < C_DIM; c4 += 4) {
        float xa[4][4];
#pragma unroll
        for (int j = 0; j < 4; ++j)
            *reinterpret_cast<float4*>(xa[j]) =
                *reinterpret_cast<const float4*>(xrow[j] + c4);
#pragma unroll
        for (int u = 0; u < 4; ++u) {
            const int c = c4 + u;
            const float wq = Wq[c * D_DIM + d];
            const float wk = Wk[c * D_DIM + d];
            const float wv = Wv[c * D_DIM + d];
#pragma unroll
            for (int j = 0; j < 4; ++j) {
                aq[j] = fmaf(xa[j][u], wq, aq[j]);
                ak[j] = fmaf(xa[j][u], wk, ak[j]);
                av[j] = fmaf(xa[j][u], wv, av[j]);
            }
        }
    }

    const float bqd = bq[d], bkd = bk[d], bvd = bv[d];
#pragma unroll
    for (int j = 0; j < 4; ++j) {
        const size_t t = t0 + (size_t)g + 4u * j;
        Q[t * D_DIM + d]  = aq[j] + bqd;
        Ko[t * D_DIM + d] = ak[j] + bkd;
        Vo[t * D_DIM + d] = av[j] + bvd;
    }
}

// ---------------------------------------------------------------------------
// Kernel 2: causal flash attention, fp32.
// Grid = (T/64, B); block = 256 threads = 4 waves. Each wave owns 16 query
// rows of the 64-row Q tile. K/V tiles (64x64) staged in LDS with +1 pad
// (conflict-free b32: bank = (65*row + d) % 32 distinct per lane).
// Online softmax per row; PV via __shfl broadcast of p (no cross-wave LDS
// hazard).
// ---------------------------------------------------------------------------
#define TQ 64
#define TK 64

__global__ __launch_bounds__(256) void attn_kernel(
    const float* __restrict__ Q, const float* __restrict__ K,
    const float* __restrict__ V, float* __restrict__ out)
{
    __shared__ float Qs[TQ][D_DIM + 1];
    __shared__ float Ks[TK][D_DIM + 1];
    __shared__ float Vs[TK][D_DIM + 1];

    const int qt   = blockIdx.x;
    const int b    = blockIdx.y;
    const int tid  = threadIdx.x;
    const int wave = tid >> 6;
    const int lane = tid & 63;
    const int row0 = wave * 16;

    const float scale = 0.125f;  // 1/sqrt(64)

    const float* Qb = Q + ((size_t)b * T_DIM + (size_t)qt * TQ) * D_DIM;
    for (int i = tid; i < TQ * D_DIM; i += 256)
        Qs[i >> 6][i & 63] = Qb[i];

    float m[16], l[16], acc[16];
#pragma unroll
    for (int r = 0; r < 16; ++r) { m[r] = NEG_BIG; l[r] = 0.f; acc[r] = 0.f; }

    for (int kt = 0; kt <= qt; ++kt) {
        __syncthreads();  // previous tile fully consumed (also covers Q load)
        const float* Kb = K + ((size_t)b * T_DIM + (size_t)kt * TK) * D_DIM;
        const float* Vb = V + ((size_t)b * T_DIM + (size_t)kt * TK) * D_DIM;
        for (int i = tid; i < TK * D_DIM; i += 256) {
            Ks[i >> 6][i & 63] = Kb[i];
            Vs[i >> 6][i & 63] = Vb[i];
        }
        __syncthreads();

        const bool diag = (kt == qt);
#pragma unroll 1
        for (int r = 0; r < 16; ++r) {
            const int qrow = row0 + r;
            // score for key index = lane
            float s = 0.f;
#pragma unroll
            for (int dd = 0; dd < D_DIM; ++dd)
                s = fmaf(Qs[qrow][dd], Ks[lane][dd], s);
            s *= scale;
            if (diag && lane > qrow) s = NEG_BIG;

            // wave-wide max
            float mx = s;
#pragma unroll
            for (int off = 32; off > 0; off >>= 1)
                mx = fmaxf(mx, __shfl_xor(mx, off));
            const float mnew = fmaxf(m[r], mx);
            const float p    = __expf(s - mnew);       // masked -> 0
            const float corr = __expf(m[r] - mnew);    // first tile -> 0, l=0 anyway

            // wave-wide sum of p
            float ps = p;
#pragma unroll
            for (int off = 32; off > 0; off >>= 1)
                ps += __shfl_xor(ps, off);

            l[r] = l[r] * corr + ps;
            m[r] = mnew;

            float a = acc[r] * corr;
#pragma unroll 1
            for (int ss = 0; ss < TK; ++ss) {
                const float pv = __shfl(p, ss);        // broadcast lane ss's p
                a = fmaf(pv, Vs[ss][lane], a);         // lane = output dim, coalesced banks
            }
            acc[r] = a;
        }
    }

    float* ob = out + ((size_t)b * T_DIM + (size_t)qt * TQ) * D_DIM;
#pragma unroll
    for (int r = 0; r < 16; ++r)
        ob[(size_t)(row0 + r) * D_DIM + lane] = acc[r] / l[r];
}

// ---------------------------------------------------------------------------
extern "C" void kernel_launch(void* const* d_in, const int* in_sizes, int n_in,
                              void* d_out, int out_size, void* d_ws, size_t ws_size,
                              hipStream_t stream)
{
    const float* x  = (const float*)d_in[0];
    const float* Wq = (const float*)d_in[1];
    const float* bq = (const float*)d_in[2];
    const float* Wk = (const float*)d_in[3];
    const float* bk = (const float*)d_in[4];
    const float* Wv = (const float*)d_in[5];
    const float* bv = (const float*)d_in[6];
    float* out = (float*)d_out;

    const size_t BTD = (size_t)B_DIM * T_DIM * D_DIM;  // 1,048,576 floats = 4 MiB
    float* Q = (float*)d_ws;         // needs 12 MiB of workspace total
    float* K = Q + BTD;
    float* V = K + BTD;

    // QKV projection: 16 rows per block
    {
        dim3 grid((B_DIM * T_DIM) / 16);
        dim3 block(256);
        qkv_proj_kernel<<<grid, block, 0, stream>>>(x, Wq, bq, Wk, bk, Wv, bv, Q, K, V);
    }

    // Attention
    {
        dim3 grid(T_DIM / TQ, B_DIM);
        dim3 block(256);
        attn_kernel<<<grid, block, 0, stream>>>(Q, K, V, out);
    }
}

// Round 2
// 66.516 us; speedup vs baseline: 31.5168x; 31.5168x over previous
//
#include <hip/hip_runtime.h>
#include <hip/hip_bf16.h>
#include <cstdint>
#include <cstddef>

typedef __attribute__((ext_vector_type(8))) short bf16x8;
typedef __attribute__((ext_vector_type(4))) float f32x4;
typedef __attribute__((ext_vector_type(4))) unsigned int u32x4;

#define T_DIM 2048
#define C_DIM 1024
#define B_DIM 8
#define NEG_BIG (-3.0e38f)

__device__ __forceinline__ unsigned short f2bf(float f) {
  union { __hip_bfloat16 h; unsigned short u; } cv;
  cv.h = __float2bfloat16(f);
  return cv.u;
}

__device__ __forceinline__ f32x4 mfma16(bf16x8 a, bf16x8 b, f32x4 c) {
  return __builtin_amdgcn_mfma_f32_16x16x32_bf16(a, b, c, 0, 0, 0);
}

// ---------------------------------------------------------------------------
// prep_w: W [1024][64] f32 -> Wt [3][64][1024] bf16 (transposed; Wq scaled 1/8)
// grid 48 = 3 matrices x 16 k-tiles
// ---------------------------------------------------------------------------
__global__ __launch_bounds__(256) void prep_w(
    const float* __restrict__ Wq, const float* __restrict__ Wk,
    const float* __restrict__ Wv, unsigned short* __restrict__ Wt)
{
  const int mtx = blockIdx.x >> 4;
  const int k0  = (blockIdx.x & 15) * 64;
  const float* W = (mtx == 0) ? Wq : ((mtx == 1) ? Wk : Wv);
  const float scale = (mtx == 0) ? 0.125f : 1.0f;
  __shared__ float Ws[64][65];
  const int t = threadIdx.x;
#pragma unroll
  for (int j = 0; j < 4; ++j) {
    int r = (t >> 4) + 16 * j;          // k-local
    int c = (t & 15) * 4;               // d
    union { float4 f4; float f[4]; } uv;
    uv.f4 = *(const float4*)&W[(size_t)(k0 + r) * 64 + c];
#pragma unroll
    for (int jj = 0; jj < 4; ++jj) Ws[c + jj][r] = uv.f[jj] * scale;
  }
  __syncthreads();
#pragma unroll
  for (int q = 0; q < 2; ++q) {
    int g_ = t + 256 * q;               // 0..511
    int d  = g_ >> 3;
    int ko = (g_ & 7) * 8;
    union { unsigned short u[8]; u32x4 v; } pk;
#pragma unroll
    for (int jj = 0; jj < 8; ++jj) pk.u[jj] = f2bf(Ws[d][ko + jj]);
    *(u32x4*)&Wt[((size_t)mtx * 64 + d) * C_DIM + k0 + ko] = pk.v;
  }
}

// ---------------------------------------------------------------------------
// qkv_proj_mfma: [16384 x 1024] x [1024 x 192] -> Qb/Kb/Vb bf16 [16384][64]
// grid 256 blocks, 64 rows each; 4 waves each own 3 of 12 n-tiles, all 4 m-tiles
// ---------------------------------------------------------------------------
__global__ __launch_bounds__(256) void qkv_proj_mfma(
    const float* __restrict__ x,
    const unsigned short* __restrict__ Wt,
    const float* __restrict__ bq, const float* __restrict__ bk, const float* __restrict__ bv,
    unsigned short* __restrict__ Qb, unsigned short* __restrict__ Kb, unsigned short* __restrict__ Vb)
{
  __shared__ short Xs[64 * 64];        // [64 rows][64 k] bf16, swizzled, stride 128B
  __shared__ short Ws[3 * 64 * 64];    // [mtx][64 n][64 k] bf16, swizzled

  const int tid = threadIdx.x;
  const int wv = tid >> 6, lane = tid & 63, g = lane >> 4, ln15 = lane & 15;
  const size_t m0 = (size_t)blockIdx.x * 64;

  f32x4 acc[4][3];
#pragma unroll
  for (int mt = 0; mt < 4; ++mt)
#pragma unroll
    for (int j = 0; j < 3; ++j) acc[mt][j] = (f32x4){0.f, 0.f, 0.f, 0.f};

  for (int kt = 0; kt < 16; ++kt) {
    __syncthreads();
    // stage X: 64x64 f32 -> bf16, coalesced float4 reads
#pragma unroll
    for (int q = 0; q < 4; ++q) {
      int g_ = tid + 256 * q;           // 0..1023 (float4 granules)
      int r = g_ >> 4, c4 = (g_ & 15) * 4;
      union { float4 f4; float f[4]; } uv;
      uv.f4 = *(const float4*)&x[(m0 + r) * C_DIM + kt * 64 + c4];
      union { unsigned short u[4]; unsigned long long ll; } pk;
#pragma unroll
      for (int jj = 0; jj < 4; ++jj) pk.u[jj] = f2bf(uv.f[jj]);
      *(unsigned long long*)((char*)Xs + r * 128 + ((c4 * 2) ^ ((r & 7) << 4))) = pk.ll;
    }
    // stage W tiles (bf16, 16B granules)
#pragma unroll
    for (int mt = 0; mt < 3; ++mt)
#pragma unroll
      for (int q = 0; q < 2; ++q) {
        int g_ = tid + 256 * q;         // 0..511
        int d = g_ >> 3, ko = (g_ & 7) * 8;
        u32x4 v = *(const u32x4*)&Wt[((size_t)mt * 64 + d) * C_DIM + kt * 64 + ko];
        *(u32x4*)((char*)Ws + mt * 8192 + d * 128 + ((ko * 2) ^ ((d & 7) << 4))) = v;
      }
    __syncthreads();
#pragma unroll
    for (int kc = 0; kc < 2; ++kc) {
      bf16x8 a[4];
#pragma unroll
      for (int mt = 0; mt < 4; ++mt) {
        int xr = mt * 16 + ln15;
        a[mt] = *(const bf16x8*)((const char*)Xs + xr * 128 + ((kc * 64 + g * 16) ^ ((xr & 7) << 4)));
      }
#pragma unroll
      for (int j = 0; j < 3; ++j) {
        int ntg = wv * 3 + j;
        int mtx = ntg >> 2, nc = (ntg & 3) * 16;
        int wrow = nc + ln15;
        bf16x8 bb = *(const bf16x8*)((const char*)Ws + mtx * 8192 + wrow * 128 + ((kc * 64 + g * 16) ^ ((wrow & 7) << 4)));
#pragma unroll
        for (int mt = 0; mt < 4; ++mt)
          acc[mt][j] = mfma16(a[mt], bb, acc[mt][j]);
      }
    }
  }
  // epilogue: bias + bf16 store
#pragma unroll
  for (int j = 0; j < 3; ++j) {
    int ntg = wv * 3 + j;
    int mtx = ntg >> 2, nc = (ntg & 3) * 16;
    const float* bias = (mtx == 0) ? bq : ((mtx == 1) ? bk : bv);
    unsigned short* Out = (mtx == 0) ? Qb : ((mtx == 1) ? Kb : Vb);
    float bsc = (mtx == 0) ? 0.125f : 1.0f;
    float bvv = bias[nc + ln15] * bsc;
#pragma unroll
    for (int mt = 0; mt < 4; ++mt)
#pragma unroll
      for (int i = 0; i < 4; ++i)
        Out[(m0 + mt * 16 + 4 * g + i) * 64 + nc + ln15] = f2bf(acc[mt][j][i] + bvv);
  }
}

// ---------------------------------------------------------------------------
// transpose_v: Vb [B*T][64] bf16 -> VTb [B][64][T] bf16
// ---------------------------------------------------------------------------
__global__ __launch_bounds__(256) void transpose_v(
    const unsigned short* __restrict__ Vb, unsigned short* __restrict__ VTb)
{
  const int tt = blockIdx.x >> 3;
  const int b  = blockIdx.x & 7;
  const int t0 = tt * 64;
  __shared__ unsigned short Vs[64][65];
  const int t = threadIdx.x;
#pragma unroll
  for (int q = 0; q < 2; ++q) {
    int g_ = t + 256 * q;               // 0..511
    int tr = g_ >> 3, dof = (g_ & 7) * 8;
    union { unsigned short u[8]; u32x4 v; } pk;
    pk.v = *(const u32x4*)&Vb[((size_t)b * T_DIM + t0 + tr) * 64 + dof];
#pragma unroll
    for (int jj = 0; jj < 8; ++jj) Vs[dof + jj][tr] = pk.u[jj];
  }
  __syncthreads();
#pragma unroll
  for (int q = 0; q < 2; ++q) {
    int g_ = t + 256 * q;
    int d = g_ >> 3, tof = (g_ & 7) * 8;
    union { unsigned short u[8]; u32x4 v; } pk;
#pragma unroll
    for (int jj = 0; jj < 8; ++jj) pk.u[jj] = Vs[d][tof + jj];
    *(u32x4*)&VTb[((size_t)b * 64 + d) * T_DIM + t0 + tof] = pk.v;
  }
}

// ---------------------------------------------------------------------------
// attn_mfma: flash attention, bf16 MFMA.
// grid 512 = 64 q-tiles (32 rows) x 8 batches, balance-paired launch order.
// 4 waves: (row half = wv&1) x (col half of 128-wide KV strip = wv>>1).
// Col halves merged via LDS at the end (flash split-k).
// ---------------------------------------------------------------------------
__global__ __launch_bounds__(256) void attn_mfma(
    const unsigned short* __restrict__ Qb,   // [B*T][64] (pre-scaled by 1/8)
    const unsigned short* __restrict__ Kb,   // [B*T][64]
    const unsigned short* __restrict__ VTb,  // [B][64][T]
    float* __restrict__ out)                 // [B*T][64] f32
{
  __shared__ short Ks[128 * 64];   // [kv][d] swizzled, stride 128B
  __shared__ short VTs[64 * 128];  // [d][kv] swizzled, stride 256B
  __shared__ short Qs[32 * 64];    // swizzled
  __shared__ short Ps[4 * 16 * 64];// per-wave P, swizzled
  __shared__ float ml2[2][16][2];

  const int tid  = threadIdx.x;
  const int wv   = tid >> 6;
  const int lane = tid & 63;
  const int g    = lane >> 4;
  const int ln15 = lane & 15;

  const int bx = blockIdx.x;
  const int qt = (bx < 256) ? (63 - (bx >> 3)) : ((bx - 256) >> 3);
  const int b  = bx & 7;
  const int r0 = qt * 32;
  const int half = wv & 1;   // q-row half (0: rows 0-15, 1: rows 16-31)
  const int ch   = wv >> 1;  // kv col half of the 128-wide strip
  const int rmax = r0 + 31;

  // stage Q once
  {
    const char* Qg = (const char*)(Qb + ((size_t)b * T_DIM + r0) * 64);
    int row = tid >> 3, bo = (tid & 7) * 16;
    u32x4 v = *(const u32x4*)(Qg + row * 128 + bo);
    *(u32x4*)((char*)Qs + row * 128 + (bo ^ ((row & 7) << 4))) = v;
  }
  __syncthreads();
  bf16x8 qa[2];
  {
    int qrow = 16 * half + ln15;
#pragma unroll
    for (int kc = 0; kc < 2; ++kc)
      qa[kc] = *(const bf16x8*)((const char*)Qs + qrow * 128 + ((kc * 64 + g * 16) ^ ((qrow & 7) << 4)));
  }

  f32x4 accv[4];
#pragma unroll
  for (int nt = 0; nt < 4; ++nt) accv[nt] = (f32x4){0.f, 0.f, 0.f, 0.f};
  float m_[4], l_[4];
#pragma unroll
  for (int i = 0; i < 4; ++i) { m_[i] = NEG_BIG; l_[i] = 0.f; }

  const int NIT = ((r0 + 31) >> 7) + 1;
  const char* Kgb  = (const char*)(Kb + (size_t)b * T_DIM * 64);
  const char* VTgb = (const char*)(VTb + (size_t)b * 64 * T_DIM);

  for (int it = 0; it < NIT; ++it) {
    const int s0 = it * 128;
    __syncthreads();
    // stage K [128][64]
#pragma unroll
    for (int q = 0; q < 4; ++q) {
      int g_ = tid + 256 * q;           // 1024 granules
      int row = g_ >> 3, bo = (g_ & 7) * 16;
      u32x4 v = *(const u32x4*)(Kgb + (size_t)(s0 + row) * 128 + bo);
      *(u32x4*)((char*)Ks + row * 128 + (bo ^ ((row & 7) << 4))) = v;
    }
    // stage VT [64][128]
#pragma unroll
    for (int q = 0; q < 4; ++q) {
      int g_ = tid + 256 * q;
      int row = g_ >> 4, bo = (g_ & 15) * 16;
      u32x4 v = *(const u32x4*)(VTgb + (size_t)row * (T_DIM * 2) + (size_t)s0 * 2 + bo);
      *(u32x4*)((char*)VTs + row * 256 + (bo ^ ((row & 7) << 4))) = v;
    }
    __syncthreads();

    const int s0w = s0 + ch * 64;
    if (s0w <= rmax) {
      // QK^T -> S [16 q][64 kv]
      f32x4 sfr[4];
#pragma unroll
      for (int nt = 0; nt < 4; ++nt) {
        f32x4 a = (f32x4){0.f, 0.f, 0.f, 0.f};
#pragma unroll
        for (int kc = 0; kc < 2; ++kc) {
          int krow = ch * 64 + nt * 16 + ln15;
          bf16x8 kb = *(const bf16x8*)((const char*)Ks + krow * 128 + ((kc * 64 + g * 16) ^ ((krow & 7) << 4)));
          a = mfma16(qa[kc], kb, a);
        }
        sfr[nt] = a;
      }
      // causal mask
      if (s0w + 63 > r0 + 16 * half) {
#pragma unroll
        for (int nt = 0; nt < 4; ++nt) {
          int colg = s0w + nt * 16 + ln15;
#pragma unroll
          for (int i = 0; i < 4; ++i) {
            int rowg = r0 + 16 * half + 4 * g + i;
            if (colg > rowg) sfr[nt][i] = NEG_BIG;
          }
        }
      }
      // online softmax (rows live in 16-lane groups)
      float mx[4], corr[4];
#pragma unroll
      for (int i = 0; i < 4; ++i)
        mx[i] = fmaxf(fmaxf(sfr[0][i], sfr[1][i]), fmaxf(sfr[2][i], sfr[3][i]));
#pragma unroll
      for (int i = 0; i < 4; ++i) {
#pragma unroll
        for (int off = 1; off < 16; off <<= 1)
          mx[i] = fmaxf(mx[i], __shfl_xor(mx[i], off));
        float mn = fmaxf(m_[i], mx[i]);
        corr[i] = __expf(m_[i] - mn);
        m_[i] = mn;
      }
#pragma unroll
      for (int nt = 0; nt < 4; ++nt)
#pragma unroll
        for (int i = 0; i < 4; ++i)
          sfr[nt][i] = __expf(sfr[nt][i] - m_[i]);
#pragma unroll
      for (int i = 0; i < 4; ++i) {
        float ps = sfr[0][i] + sfr[1][i] + sfr[2][i] + sfr[3][i];
#pragma unroll
        for (int off = 1; off < 16; off <<= 1)
          ps += __shfl_xor(ps, off);
        l_[i] = l_[i] * corr[i] + ps;
      }
#pragma unroll
      for (int nt = 0; nt < 4; ++nt)
#pragma unroll
        for (int i = 0; i < 4; ++i)
          accv[nt][i] *= corr[i];
      // P -> bf16 -> per-wave LDS (swizzled)
#pragma unroll
      for (int nt = 0; nt < 4; ++nt)
#pragma unroll
        for (int i = 0; i < 4; ++i) {
          int r_ = 4 * g + i;
          int cbo = (nt * 16 + ln15) * 2;
          *(unsigned short*)((char*)Ps + wv * 2048 + r_ * 128 + (cbo ^ ((r_ & 7) << 4))) = f2bf(sfr[nt][i]);
        }
      // PV
#pragma unroll
      for (int kc = 0; kc < 2; ++kc) {
        bf16x8 pa = *(const bf16x8*)((const char*)Ps + wv * 2048 + ln15 * 128 + ((kc * 64 + g * 16) ^ ((ln15 & 7) << 4)));
#pragma unroll
        for (int nt = 0; nt < 4; ++nt) {
          int vrow = nt * 16 + ln15;
          bf16x8 vb = *(const bf16x8*)((const char*)VTs + vrow * 256 + ((ch * 128 + kc * 64 + g * 16) ^ ((vrow & 7) << 4)));
          accv[nt] = mfma16(pa, vb, accv[nt]);
        }
      }
    }
  }

  // merge the two col-halves
  __syncthreads();
  float* Z2 = (float*)Ks;   // reuse K region: 2 x 16 x 64 f32
  if (ch == 1) {
#pragma unroll
    for (int nt = 0; nt < 4; ++nt)
#pragma unroll
      for (int i = 0; i < 4; ++i)
        Z2[half * 1024 + (4 * g + i) * 64 + nt * 16 + ln15] = accv[nt][i];
    if (ln15 == 0) {
#pragma unroll
      for (int i = 0; i < 4; ++i) {
        ml2[half][4 * g + i][0] = m_[i];
        ml2[half][4 * g + i][1] = l_[i];
      }
    }
  }
  __syncthreads();
  if (ch == 0) {
    float c1[4], c2[4];
#pragma unroll
    for (int i = 0; i < 4; ++i) {
      float m2 = ml2[half][4 * g + i][0];
      float l2 = ml2[half][4 * g + i][1];
      float mm = fmaxf(m_[i], m2);
      float e1 = __expf(m_[i] - mm), e2 = __expf(m2 - mm);
      float inv = 1.0f / (l_[i] * e1 + l2 * e2);
      c1[i] = e1 * inv; c2[i] = e2 * inv;
    }
    float* ob = out + ((size_t)b * T_DIM + r0 + 16 * half) * 64;
#pragma unroll
    for (int nt = 0; nt < 4; ++nt)
#pragma unroll
      for (int i = 0; i < 4; ++i) {
        float z2 = Z2[half * 1024 + (4 * g + i) * 64 + nt * 16 + ln15];
        ob[(size_t)(4 * g + i) * 64 + nt * 16 + ln15] = accv[nt][i] * c1[i] + z2 * c2[i];
      }
  }
}

// ---------------------------------------------------------------------------
extern "C" void kernel_launch(void* const* d_in, const int* in_sizes, int n_in,
                              void* d_out, int out_size, void* d_ws, size_t ws_size,
                              hipStream_t stream)
{
  const float* x  = (const float*)d_in[0];
  const float* Wq = (const float*)d_in[1];
  const float* bq = (const float*)d_in[2];
  const float* Wk = (const float*)d_in[3];
  const float* bk = (const float*)d_in[4];
  const float* Wv = (const float*)d_in[5];
  const float* bv = (const float*)d_in[6];
  float* out = (float*)d_out;

  char* ws = (char*)d_ws;
  unsigned short* Wt  = (unsigned short*)(ws);                          // 384 KB
  unsigned short* Qb  = (unsigned short*)(ws + (1u << 19));             // 2 MB
  unsigned short* Kb  = (unsigned short*)(ws + (1u << 19) + (1u << 21));
  unsigned short* Vb  = (unsigned short*)(ws + (1u << 19) + (2u << 21));
  unsigned short* VTb = (unsigned short*)(ws + (1u << 19) + (3u << 21));

  prep_w<<<48, 256, 0, stream>>>(Wq, Wk, Wv, Wt);
  qkv_proj_mfma<<<256, 256, 0, stream>>>(x, Wt, bq, bk, bv, Qb, Kb, Vb);
  transpose_v<<<256, 256, 0, stream>>>(Vb, VTb);
  attn_mfma<<<512, 256, 0, stream>>>(Qb, Kb, VTb, out);
}